// Round 1
// baseline (179.560 us; speedup 1.0000x reference)
//
#include <hip/hip_runtime.h>

// Adaptive separable conv (SepConv): out[b,c,y,x] = sum_i sum_j inp[b,c,y+i,x+j]*v[b,i,y,x]*h[b,j,y,x]
// B=2,C=3,H=W=256,K=51. fp32 in/out. No MFMA path (per-pixel weights; no fp32 MFMA on CDNA4).
//
// Structure: 32x8 output tile per block; thread = 4 x-adjacent outputs x 3 channels,
// 1/4 of the i-taps (i-split across the 4 waves, LDS reduction at end).
// inp tile staged in LDS (3x58x84 = 58.5KB -> 2 blocks/CU, 8 waves/CU).
// Inner loop: 2D (i0 x j0) register blocking, rolling 8-float window per (c,ib) so each
// ds_read_b128 feeds 16 FMAs. v: read once (global float4). h: streamed from global per
// (i0,j0) chunk, re-read x(num i0 blocks) -> ~400MB L2 traffic on the idle VMEM pipe.

namespace {
constexpr int KK = 51;
constexpr int NB = 2;
constexpr int NC = 3;
constexpr int HH = 256;
constexpr int WW = 256;
constexpr int IN_H = HH + KK - 1;   // 306
constexpr int IN_W = WW + KK - 1;   // 306

constexpr int TILE_W = 32;          // output cols per block
constexpr int TILE_H = 8;           // output rows per block
constexpr int NTX = 8;              // threads along x (each covers R=4 outputs)
constexpr int R = 4;
constexpr int NTY = 8;
constexpr int NS = 4;               // i-tap split (one range per wave)
constexpr int HALO_W = TILE_W + KK - 1;  // 82
constexpr int LDS_W = 84;           // padded cols (82 valid + 2 zero pad)
constexpr int LDS_H = TILE_H + KK - 1;   // 58
constexpr int BI = 4;               // i-taps per register block
}

__device__ __forceinline__ float fget(const float4 v, int i) {
  return (i == 0) ? v.x : (i == 1) ? v.y : (i == 2) ? v.z : v.w;
}

__global__ __launch_bounds__(256, 1) void sepconv_kernel(
    const float* __restrict__ inp,
    const float* __restrict__ vert,
    const float* __restrict__ horiz,
    float* __restrict__ out)
{
  __shared__ float lds[NC * LDS_H * LDS_W];   // 58,464 B

  const int tid = threadIdx.x;
  const int tx  = tid & (NTX - 1);
  const int ty  = (tid >> 3) & (NTY - 1);
  const int s   = tid >> 6;                    // wave id: 0..3 (wave-uniform)

  const int x0 = blockIdx.x * TILE_W;
  const int y0 = blockIdx.y * TILE_H;
  const int bz = blockIdx.z;

  // ---- Stage input tile: 3ch x 58 rows x 82 cols (float2-vectorized), zero the 2 pad cols.
  {
    const float* src = inp + ((size_t)(bz * NC) * IN_H + y0) * IN_W + x0;
    const int total2 = NC * LDS_H * (HALO_W / 2);   // 3*58*41
    for (int e = tid; e < total2; e += 256) {
      int col2 = e % (HALO_W / 2);
      int t    = e / (HALO_W / 2);
      int r    = t % LDS_H;
      int c    = t / LDS_H;
      const float2 v = *reinterpret_cast<const float2*>(src + ((size_t)c * IN_H + r) * IN_W + col2 * 2);
      float* dst = &lds[(c * LDS_H + r) * LDS_W + col2 * 2];
      dst[0] = v.x; dst[1] = v.y;
    }
    for (int e = tid; e < NC * LDS_H * (LDS_W - HALO_W); e += 256) {
      int p = e % (LDS_W - HALO_W);
      int t = e / (LDS_W - HALO_W);
      int r = t % LDS_H;
      int c = t / LDS_H;
      lds[(c * LDS_H + r) * LDS_W + HALO_W + p] = 0.0f;
    }
  }
  __syncthreads();

  const int lx = tx * R;                 // local LDS col base (16B aligned)
  const int xg = x0 + lx;                // global x of first output
  const int yg = y0 + ty;                // global y

  float acc[R][NC];
#pragma unroll
  for (int rx = 0; rx < R; ++rx)
#pragma unroll
    for (int c = 0; c < NC; ++c) acc[rx][c] = 0.0f;

  // i-tap split: s<3 -> 13 taps, s==3 -> 12 taps
  const int sbase  = 13 * s;
  const int scount = (s < 3) ? 13 : 12;
  const int nblk   = (scount + BI - 1) / BI;   // 4,4,4,3 (wave-uniform)

  const float* vbase = vert  + (((size_t)bz * KK) * HH + yg) * WW + xg;
  const float* hbase = horiz + (((size_t)bz * KK) * HH + yg) * WW + xg;
  constexpr int KSTRIDE = HH * WW;       // per-tap stride in v/h

  for (int i0 = 0; i0 < nblk; ++i0) {
    const int ibase = sbase + i0 * BI;

    // Per-block vertical weights (read-once). Masked slots -> 0.
    float4 v4[BI];
#pragma unroll
    for (int ib = 0; ib < BI; ++ib) {
      const int i = ibase + ib;
      float4 t = *reinterpret_cast<const float4*>(vbase + (size_t)i * KSTRIDE);
      if (i >= sbase + scount) t = make_float4(0.f, 0.f, 0.f, 0.f);
      v4[ib] = t;
    }

    // Init rolling windows: w = cols [0,8), nx = cols [8,12) (relative to lx)
    float  w[NC][BI][8];
    float4 nx[NC][BI];
#pragma unroll
    for (int c = 0; c < NC; ++c) {
#pragma unroll
      for (int ib = 0; ib < BI; ++ib) {
        const int rr = ty + ibase + ib;    // <= 7+50 = 57, in bounds (masked i <= 41)
        const float4* p = reinterpret_cast<const float4*>(&lds[(c * LDS_H + rr) * LDS_W + lx]);
        float4 a = p[0], b = p[1];
        w[c][ib][0] = a.x; w[c][ib][1] = a.y; w[c][ib][2] = a.z; w[c][ib][3] = a.w;
        w[c][ib][4] = b.x; w[c][ib][5] = b.y; w[c][ib][6] = b.z; w[c][ib][7] = b.w;
        nx[c][ib] = p[2];
      }
    }

    // Prefetch horizontal weights for chunk j0=0
    float4 h4[4];
#pragma unroll
    for (int jj = 0; jj < 4; ++jj)
      h4[jj] = *reinterpret_cast<const float4*>(hbase + (size_t)jj * KSTRIDE);

#pragma unroll
    for (int j0 = 0; j0 < 52; j0 += 4) {   // 13 chunks of 4 j-taps
      float4 hc[4];
#pragma unroll
      for (int jj = 0; jj < 4; ++jj) hc[jj] = h4[jj];

      // Prefetch next chunk's h (mask j=51 -> 0)
      if (j0 < 48) {
#pragma unroll
        for (int jj = 0; jj < 4; ++jj) {
          const int j = j0 + 4 + jj;
          const int jc = (j <= 50) ? j : 50;
          float4 t = *reinterpret_cast<const float4*>(hbase + (size_t)jc * KSTRIDE);
          if (j > 50) t = make_float4(0.f, 0.f, 0.f, 0.f);
          h4[jj] = t;
        }
      }

      // coeff = v*h hoisted across the 3 channels: 64 muls + 192 FMAs per chunk
#pragma unroll
      for (int rx = 0; rx < R; ++rx) {
#pragma unroll
        for (int ib = 0; ib < BI; ++ib) {
          const float vv = fget(v4[ib], rx);
#pragma unroll
          for (int jj = 0; jj < 4; ++jj) {
            const float cf = vv * fget(hc[jj], rx);
#pragma unroll
            for (int c = 0; c < NC; ++c)
              acc[rx][c] = fmaf(cf, w[c][ib][rx + jj], acc[rx][c]);
          }
        }
      }

      // Rotate windows and prefetch next quad
      if (j0 < 48) {
#pragma unroll
        for (int c = 0; c < NC; ++c) {
#pragma unroll
          for (int ib = 0; ib < BI; ++ib) {
#pragma unroll
            for (int q = 0; q < 4; ++q) w[c][ib][q] = w[c][ib][q + 4];
            float4 n = nx[c][ib];
            w[c][ib][4] = n.x; w[c][ib][5] = n.y; w[c][ib][6] = n.z; w[c][ib][7] = n.w;
            if (j0 + 8 < 52) {
              const int rr = ty + ibase + ib;
              nx[c][ib] = *reinterpret_cast<const float4*>(
                  &lds[(c * LDS_H + rr) * LDS_W + lx + j0 + 12]);
            }
          }
        }
      }
    }
  }

  // ---- Reduce the 4 i-split partials (waves 1..3 -> LDS, wave 0 adds & stores)
  __syncthreads();   // all LDS inp reads done; safe to reuse
  if (s > 0) {
    float* p = &lds[((s - 1) * 64 + ty * NTX + tx) * 12];
#pragma unroll
    for (int rx = 0; rx < R; ++rx)
#pragma unroll
      for (int c = 0; c < NC; ++c) p[rx * 3 + c] = acc[rx][c];
  }
  __syncthreads();
  if (s == 0) {
#pragma unroll
    for (int g = 0; g < 3; ++g) {
      const float* p = &lds[(g * 64 + ty * NTX + tx) * 12];
#pragma unroll
      for (int rx = 0; rx < R; ++rx)
#pragma unroll
        for (int c = 0; c < NC; ++c) acc[rx][c] += p[rx * 3 + c];
    }
#pragma unroll
    for (int c = 0; c < NC; ++c) {
      float4 o = make_float4(acc[0][c], acc[1][c], acc[2][c], acc[3][c]);
      *reinterpret_cast<float4*>(out + (((size_t)bz * NC + c) * HH + yg) * WW + xg) = o;
    }
  }
}

extern "C" void kernel_launch(void* const* d_in, const int* in_sizes, int n_in,
                              void* d_out, int out_size, void* d_ws, size_t ws_size,
                              hipStream_t stream) {
  const float* inp   = (const float*)d_in[0];
  const float* vert  = (const float*)d_in[1];
  const float* horiz = (const float*)d_in[2];
  float* out = (float*)d_out;

  dim3 grid(WW / TILE_W, HH / TILE_H, NB);   // 8 x 32 x 2 = 512 blocks
  sepconv_kernel<<<grid, NTX * NTY * NS, 0, stream>>>(inp, vert, horiz, out);
}